// Round 4
// baseline (448.804 us; speedup 1.0000x reference)
//
#include <hip/hip_runtime.h>

#define BATCH 1024
#define NNODE 92
#define FIN   1024
#define FOUT  512

typedef float    f32x4 __attribute__((ext_vector_type(4)));
typedef _Float16 half8 __attribute__((ext_vector_type(8)));
typedef _Float16 half4 __attribute__((ext_vector_type(4)));

__device__ __forceinline__ float lrelu(float x) { return fmaxf(x, 0.2f * x); }

// ---------------------------------------------------------------------------
// prep: WT[n][k] = f16(W[k][n]);  ATp[j][k] = f16(A[k][j]) padded [96][104]
// ---------------------------------------------------------------------------
__global__ __launch_bounds__(256) void prep_kernel(
    const float* __restrict__ W, const float* __restrict__ Am,
    _Float16* __restrict__ WT, _Float16* __restrict__ ATp) {
  int bid = blockIdx.x, t = threadIdx.x;
  if (bid < 64) {
    int n0 = bid * 8;
    for (int it = 0; it < 4; ++it) {
      int k = it * 256 + t;
      const f32x4* src = (const f32x4*)(W + (size_t)k * FOUT + n0);
      f32x4 v0 = src[0], v1 = src[1];
      #pragma unroll
      for (int c = 0; c < 4; ++c) {
        WT[(size_t)(n0 + c) * FIN + k]     = (_Float16)v0[c];
        WT[(size_t)(n0 + 4 + c) * FIN + k] = (_Float16)v1[c];
      }
    }
  } else {
    int j0 = (bid - 64) * 24;
    for (int idx = t; idx < 24 * 104; idx += 256) {
      int jr = idx / 104, k = idx - jr * 104;
      int j = j0 + jr;
      float v = (j < NNODE && k < NNODE) ? Am[k * NNODE + j] : 0.f;
      ATp[j * 104 + k] = (_Float16)v;
    }
  }
}

// ---------------------------------------------------------------------------
// K1: Wh = X @ W. 1472 blocks x 512 thr. Tile 64m x 512n (full N), BK=32,
//     double-buffered, loads early. 8 waves, 64x64 per wave. 2 blocks/CU.
//     Conflict-free LDS swizzle: Lrow = row^((row>>2)&1), slot ^= row&3.
//     Epilogue: Wh1/Wh2 = acc . a (free), then m-major LDS transpose ->
//     coalesced Wh[b][f][96] f16 stores.
// ---------------------------------------------------------------------------
__global__ __launch_bounds__(512, 4) void gemm_kernel(
    const float* __restrict__ X, const _Float16* __restrict__ WT,
    const float* __restrict__ av, _Float16* __restrict__ Wh,
    float* __restrict__ Wh1g, float* __restrict__ Wh2g) {
  extern __shared__ char smem[];
  _Float16* Al0 = (_Float16*)(smem);            //  4096 B [64][32] swz
  _Float16* Al1 = (_Float16*)(smem + 4096);
  _Float16* Bl0 = (_Float16*)(smem + 8192);     // 32768 B [512][32] swz
  _Float16* Bl1 = (_Float16*)(smem + 40960);
  _Float16* tbuf = (_Float16*)smem;             // [64][513] m-major, 65664 B
  float* red = (float*)smem;                    // [64][16] floats, 4096 B

  int t = threadIdx.x;
  int l = t & 63, w = t >> 6;
  unsigned m0 = (unsigned)blockIdx.x * 64u;

  // X load / A write mapping
  int arow = t >> 3, k8 = t & 7;
  const float* Xbase = X + ((size_t)m0 + arow) * FIN + k8 * 4;
  int awoff = ((arow ^ ((arow >> 2) & 1)) * 64) +
              ((((k8 >> 1) ^ (arow & 3)) << 4)) + ((k8 & 1) * 8);

  // B glds source mapping (matching involution of the read swizzle)
  int Lr = l >> 2, lslot = l & 3;
  int nr16 = Lr ^ ((Lr >> 2) & 1);
  int srcb = (lslot ^ (nr16 & 3)) << 4;
  int bn[4];
  #pragma unroll
  for (int p = 0; p < 4; ++p) bn[p] = p * 128 + w * 16 + nr16;

  // fragment read offsets
  int rsw = (l & 15) ^ ((l >> 2) & 1);
  int ssw = ((l >> 4) ^ (l & 3)) << 4;
  int aoff[4], boff[4];
  #pragma unroll
  for (int mi = 0; mi < 4; ++mi) aoff[mi] = (mi * 16 + rsw) * 64 + ssw;
  #pragma unroll
  for (int ni = 0; ni < 4; ++ni) boff[ni] = (w * 64 + ni * 16 + rsw) * 64 + ssw;

  // a-vector values for the fused Wh1/Wh2 output reduction
  float aC1[4], aC2[4];
  #pragma unroll
  for (int ni = 0; ni < 4; ++ni) {
    int C = w * 64 + ni * 16 + (l & 15);
    aC1[ni] = av[C];
    aC2[ni] = av[FOUT + C];
  }

  f32x4 zz = {0.f, 0.f, 0.f, 0.f};
  f32x4 acc[4][4];
  #pragma unroll
  for (int mi = 0; mi < 4; ++mi)
    #pragma unroll
    for (int ni = 0; ni < 4; ++ni) acc[mi][ni] = zz;

  f32x4 xvA, xvB;

#define K1_XLOAD(XV, KT) (XV) = *(const f32x4*)(Xbase + (size_t)(KT) * 32)

#define K1_GLDS(NB, KT) do {                                                   \
    _Pragma("unroll")                                                          \
    for (int p = 0; p < 4; ++p) {                                              \
      const _Float16* gp = WT + (size_t)bn[p] * FIN + (KT) * 32 + (srcb >> 1); \
      char* lp = (char*)(NB) + p * 8192 + w * 1024;                            \
      __builtin_amdgcn_global_load_lds(                                        \
          (const __attribute__((address_space(1))) void*)gp,                   \
          (__attribute__((address_space(3))) void*)lp, 16, 0, 0);              \
    }                                                                          \
  } while (0)

#define K1_AWRITE(NA, XV) do {                                                 \
    half4 h;                                                                   \
    h[0] = (_Float16)(XV)[0]; h[1] = (_Float16)(XV)[1];                        \
    h[2] = (_Float16)(XV)[2]; h[3] = (_Float16)(XV)[3];                        \
    *(half4*)((char*)(NA) + awoff) = h;                                        \
  } while (0)

#define K1_MFMA(CA, CB) do {                                                   \
    half8 af[4], bf[4];                                                        \
    _Pragma("unroll")                                                          \
    for (int mi = 0; mi < 4; ++mi)                                             \
      af[mi] = *(const half8*)((const char*)(CA) + aoff[mi]);                  \
    _Pragma("unroll")                                                          \
    for (int ni = 0; ni < 4; ++ni)                                             \
      bf[ni] = *(const half8*)((const char*)(CB) + boff[ni]);                  \
    _Pragma("unroll")                                                          \
    for (int mi = 0; mi < 4; ++mi)                                             \
      _Pragma("unroll")                                                        \
      for (int ni = 0; ni < 4; ++ni)                                           \
        acc[mi][ni] = __builtin_amdgcn_mfma_f32_16x16x32_f16(                  \
            af[mi], bf[ni], acc[mi][ni], 0, 0, 0);                             \
  } while (0)

  // prologue
  K1_XLOAD(xvA, 0);
  K1_GLDS(Bl0, 0);
  K1_AWRITE(Al0, xvA);
  K1_XLOAD(xvA, 1);
  __syncthreads();

  for (int kt = 0; kt < 32; kt += 2) {
    if (kt + 2 < 32) K1_XLOAD(xvB, kt + 2);
    if (kt + 1 < 32) K1_GLDS(Bl1, kt + 1);
    K1_MFMA(Al0, Bl0);
    if (kt + 1 < 32) K1_AWRITE(Al1, xvA);
    __syncthreads();
    if (kt + 3 < 32) K1_XLOAD(xvA, kt + 3);
    if (kt + 2 < 32) K1_GLDS(Bl0, kt + 2);
    K1_MFMA(Al1, Bl1);
    if (kt + 2 < 32) K1_AWRITE(Al0, xvB);
    __syncthreads();
  }

  // ---- Wh1/Wh2: per-lane partials over the 4 owned C-columns, shfl-reduce
  float p1[4][4], p2[4][4];
  #pragma unroll
  for (int mi = 0; mi < 4; ++mi)
    #pragma unroll
    for (int r = 0; r < 4; ++r) {
      float s1 = 0.f, s2 = 0.f;
      #pragma unroll
      for (int ni = 0; ni < 4; ++ni) {
        s1 = fmaf(acc[mi][ni][r], aC1[ni], s1);
        s2 = fmaf(acc[mi][ni][r], aC2[ni], s2);
      }
      p1[mi][r] = s1; p2[mi][r] = s2;
    }
  #pragma unroll
  for (int mm = 1; mm < 16; mm <<= 1)
    #pragma unroll
    for (int mi = 0; mi < 4; ++mi)
      #pragma unroll
      for (int r = 0; r < 4; ++r) {
        p1[mi][r] += __shfl_xor(p1[mi][r], mm);
        p2[mi][r] += __shfl_xor(p2[mi][r], mm);
      }
  if ((l & 15) == 0) {
    #pragma unroll
    for (int mi = 0; mi < 4; ++mi)
      #pragma unroll
      for (int r = 0; r < 4; ++r) {
        int m = mi * 16 + (l >> 4) * 4 + r;
        red[m * 16 + w * 2]     = p1[mi][r];
        red[m * 16 + w * 2 + 1] = p2[mi][r];
      }
  }
  __syncthreads();
  if (t < 64) {
    float s1 = 0.f, s2 = 0.f;
    #pragma unroll
    for (int w8 = 0; w8 < 8; ++w8) {
      s1 += red[t * 16 + w8 * 2];
      s2 += red[t * 16 + w8 * 2 + 1];
    }
    Wh1g[m0 + t] = s1;
    Wh2g[m0 + t] = s2;
  }
  __syncthreads();

  // ---- dump acc -> tbuf m-major [64][513]
  #pragma unroll
  for (int mi = 0; mi < 4; ++mi)
    #pragma unroll
    for (int ni = 0; ni < 4; ++ni) {
      int C = w * 64 + ni * 16 + (l & 15);
      #pragma unroll
      for (int r = 0; r < 4; ++r) {
        int m = mi * 16 + (l >> 4) * 4 + r;
        tbuf[m * 513 + C] = (_Float16)acc[mi][ni][r];
      }
    }
  __syncthreads();

  // ---- coalesced stores: thread t owns column C=t of Wh[b][f][96]
  unsigned mEnd = m0 + 64u;
  unsigned b0 = m0 / 92u;
  #pragma unroll 1
  for (unsigned seg = 0; seg < 2; ++seg) {
    unsigned bbase = b0 + seg;
    unsigned bstart = bbase * 92u;
    if (bstart >= mEnd) break;
    unsigned s = (bstart < m0) ? (m0 - bstart) : 0u;
    unsigned e = (mEnd - bstart < 92u) ? (mEnd - bstart) : 92u;
    if (s >= e) continue;
    _Float16* gp = Wh + ((size_t)bbase * FOUT + t) * 96;
    for (unsigned m8 = s & ~7u; m8 < e; m8 += 8) {
      unsigned lo = (m8 < s) ? s : m8;
      unsigned hi = (m8 + 8 > e) ? e : m8 + 8;
      if (hi - lo == 8) {
        half8 v;
        #pragma unroll
        for (int q = 0; q < 8; ++q)
          v[q] = tbuf[(bstart + lo - m0 + q) * 513 + t];
        *(half8*)(gp + lo) = v;
      } else {
        for (unsigned m = lo; m < hi; ++m)
          gp[m] = tbuf[(bstart + m - m0) * 513 + t];
      }
    }
  }
}

// ---------------------------------------------------------------------------
// K2: per-batch attention, no Wh staging. LDS: at_[96][104], e0a[96][104].
//     e0 -> e=lrelu(e0@A) (waves 0-5) -> mask+softmax in-reg -> att ->
//     out = att@Wh + bias with B-frags loaded straight from global Wh
//     (16B/lane coalesced, each element read once). PV in 2 f-passes.
// ---------------------------------------------------------------------------
__global__ __launch_bounds__(512, 4) void attn_kernel(
    const _Float16* __restrict__ Wh, const _Float16* __restrict__ ATp,
    const int* __restrict__ adj, const float* __restrict__ Wh1g,
    const float* __restrict__ Wh2g, const float* __restrict__ bias,
    float* __restrict__ out) {
  __shared__ __align__(16) _Float16 at_[96 * 104];
  __shared__ __align__(16) _Float16 e0a[96 * 104];
  __shared__ float w1s[96], w2s[96];

  int t = threadIdx.x, l = t & 63, w = t >> 6;
  int b = blockIdx.x;
  const _Float16* WhB = Wh + (size_t)b * FOUT * 96;

  for (int idx = t; idx < 1248; idx += 512)
    *(half8*)(at_ + idx * 8) = *(const half8*)(ATp + idx * 8);
  if (t < 96) w1s[t] = (t < 92) ? Wh1g[(size_t)b * NNODE + t] : 0.f;
  else if (t < 192) {
    int j = t - 96;
    w2s[j] = (j < 92) ? Wh2g[(size_t)b * NNODE + j] : 0.f;
  }
  __syncthreads();

  // e0[i][k] = lrelu(Wh1[i]+Wh2[k]), zero-padded to [96][104]
  for (int idx = t; idx < 96 * 128; idx += 512) {
    int i = idx >> 7, k = idx & 127;
    if (k < 104) {
      float v = (i < 92 && k < 92) ? lrelu(w1s[i] + w2s[k]) : 0.f;
      e0a[i * 104 + k] = (_Float16)v;
    }
  }
  __syncthreads();

  if (w < 6) {
    f32x4 ez = {0.f, 0.f, 0.f, 0.f};
    f32x4 eacc[6];
    #pragma unroll
    for (int ni = 0; ni < 6; ++ni) eacc[ni] = ez;
    #pragma unroll
    for (int ks = 0; ks < 3; ++ks) {
      half8 ea = *(const half8*)((const char*)e0a +
                 (16 * w + (l & 15)) * 208 + ks * 64 + (l >> 4) * 16);
      #pragma unroll
      for (int ni = 0; ni < 6; ++ni) {
        half8 bt = *(const half8*)((const char*)at_ +
                   (16 * ni + (l & 15)) * 208 + ks * 64 + (l >> 4) * 16);
        eacc[ni] = __builtin_amdgcn_mfma_f32_16x16x32_f16(ea, bt, eacc[ni], 0, 0, 0);
      }
    }
    float attv[4][6];
    #pragma unroll
    for (int r = 0; r < 4; ++r) {
      int i = 16 * w + (l >> 4) * 4 + r;
      float s[6]; float m = -3.0e38f;
      #pragma unroll
      for (int ni = 0; ni < 6; ++ni) {
        int j = ni * 16 + (l & 15);
        float e = lrelu(eacc[ni][r]);
        float sv = -3.0e38f;
        if (i < 92 && j < 92) {
          int avj = adj[((size_t)b * NNODE + i) * NNODE + j];
          sv = (avj > 0) ? e : -9.0e15f;
        }
        s[ni] = sv;
        m = fmaxf(m, sv);
      }
      #pragma unroll
      for (int mm = 1; mm < 16; mm <<= 1) m = fmaxf(m, __shfl_xor(m, mm));
      float sum = 0.f; float p[6];
      #pragma unroll
      for (int ni = 0; ni < 6; ++ni) {
        int j = ni * 16 + (l & 15);
        p[ni] = (i < 92 && j < 92) ? __expf(s[ni] - m) : 0.f;
        sum += p[ni];
      }
      #pragma unroll
      for (int mm = 1; mm < 16; mm <<= 1) sum += __shfl_xor(sum, mm);
      float rs = (i < 92) ? (1.0f / sum) : 0.f;
      #pragma unroll
      for (int ni = 0; ni < 6; ++ni) attv[r][ni] = p[ni] * rs;
    }
    // att write back into e0a (wave writes only the rows it read)
    #pragma unroll
    for (int r = 0; r < 4; ++r) {
      int i = 16 * w + (l >> 4) * 4 + r;
      #pragma unroll
      for (int ni = 0; ni < 6; ++ni)
        e0a[i * 104 + ni * 16 + (l & 15)] = (_Float16)attv[r][ni];
    }
  }
  __syncthreads();   // att visible to all waves

  // PV: out = att @ Wh, two f-passes of 32 columns per wave
  #pragma unroll 1
  for (int pp = 0; pp < 2; ++pp) {
    int f0 = pp * 256 + w * 32;
    half8 bf[3][2];
    #pragma unroll
    for (int ks = 0; ks < 3; ++ks)
      #pragma unroll
      for (int ni = 0; ni < 2; ++ni)
        bf[ks][ni] = *(const half8*)(WhB +
            (size_t)(f0 + ni * 16 + (l & 15)) * 96 + ks * 32 + (l >> 4) * 8);
    f32x4 pz = {0.f, 0.f, 0.f, 0.f};
    f32x4 pacc[6][2];
    #pragma unroll
    for (int mi = 0; mi < 6; ++mi)
      #pragma unroll
      for (int ni = 0; ni < 2; ++ni) pacc[mi][ni] = pz;
    #pragma unroll
    for (int ks = 0; ks < 3; ++ks) {
      half8 af[6];
      #pragma unroll
      for (int mi = 0; mi < 6; ++mi)
        af[mi] = *(const half8*)((const char*)e0a +
                 (16 * mi + (l & 15)) * 208 + ks * 64 + (l >> 4) * 16);
      #pragma unroll
      for (int mi = 0; mi < 6; ++mi)
        #pragma unroll
        for (int ni = 0; ni < 2; ++ni)
          pacc[mi][ni] = __builtin_amdgcn_mfma_f32_16x16x32_f16(
              af[mi], bf[ks][ni], pacc[mi][ni], 0, 0, 0);
    }
    #pragma unroll
    for (int ni = 0; ni < 2; ++ni) {
      int fcol = f0 + ni * 16 + (l & 15);
      float bv = bias[fcol];
      #pragma unroll
      for (int mi = 0; mi < 6; ++mi)
        #pragma unroll
        for (int r = 0; r < 4; ++r) {
          int i = 16 * mi + (l >> 4) * 4 + r;
          if (i < 92)
            out[((size_t)b * NNODE + i) * FOUT + fcol] = pacc[mi][ni][r] + bv;
        }
    }
  }
}

// ---------------------------------------------------------------------------
extern "C" void kernel_launch(void* const* d_in, const int* in_sizes, int n_in,
                              void* d_out, int out_size, void* d_ws, size_t ws_size,
                              hipStream_t stream) {
  (void)in_sizes; (void)n_in; (void)out_size; (void)ws_size;
  const float* X    = (const float*)d_in[0];
  const int*   adj  = (const int*)d_in[1];
  const float* W    = (const float*)d_in[2];
  const float* av   = (const float*)d_in[3];
  const float* Am   = (const float*)d_in[4];
  const float* bias = (const float*)d_in[5];
  float* out = (float*)d_out;
  char* ws = (char*)d_ws;

  _Float16* WT  = (_Float16*)(ws);              // 1,048,576 B
  _Float16* ATp = (_Float16*)(ws + 1048576);    //    19,968 B
  float* Wh1 = (float*)(ws + 1068544);          //   376,832 B
  float* Wh2 = (float*)(ws + 1445376);          //   376,832 B
  _Float16* Wh = (_Float16*)(ws + 1822208);     // 100,663,296 B  [b][f][96]

  prep_kernel<<<68, 256, 0, stream>>>(W, Am, WT, ATp);
  hipFuncSetAttribute((const void*)gemm_kernel,
                      hipFuncAttributeMaxDynamicSharedMemorySize, 73728);
  gemm_kernel<<<1472, 512, 73728, stream>>>(X, WT, av, Wh, Wh1, Wh2);
  attn_kernel<<<1024, 512, 0, stream>>>(Wh, ATp, adj, Wh1, Wh2, bias, out);
}

// Round 5
// 344.796 us; speedup vs baseline: 1.3016x; 1.3016x over previous
//
#include <hip/hip_runtime.h>

#define BATCH 1024
#define NNODE 92
#define FIN   1024
#define FOUT  512

typedef float    f32x4 __attribute__((ext_vector_type(4)));
typedef _Float16 half8 __attribute__((ext_vector_type(8)));
typedef _Float16 half4 __attribute__((ext_vector_type(4)));

__device__ __forceinline__ float lrelu(float x) { return fmaxf(x, 0.2f * x); }

#define BAR_LGKM() do {                                                        \
    asm volatile("s_waitcnt lgkmcnt(0)" ::: "memory");                         \
    __builtin_amdgcn_sched_barrier(0);                                         \
    __builtin_amdgcn_s_barrier();                                              \
  } while (0)

// ---------------------------------------------------------------------------
// prep: WT[n][k] = f16(W[k][n]);  ATp[j][k] = f16(A[k][j]) padded [96][104]
// ---------------------------------------------------------------------------
__global__ __launch_bounds__(256) void prep_kernel(
    const float* __restrict__ W, const float* __restrict__ Am,
    _Float16* __restrict__ WT, _Float16* __restrict__ ATp) {
  int bid = blockIdx.x, t = threadIdx.x;
  if (bid < 64) {
    int n0 = bid * 8;
    for (int it = 0; it < 4; ++it) {
      int k = it * 256 + t;
      const f32x4* src = (const f32x4*)(W + (size_t)k * FOUT + n0);
      f32x4 v0 = src[0], v1 = src[1];
      #pragma unroll
      for (int c = 0; c < 4; ++c) {
        WT[(size_t)(n0 + c) * FIN + k]     = (_Float16)v0[c];
        WT[(size_t)(n0 + 4 + c) * FIN + k] = (_Float16)v1[c];
      }
    }
  } else {
    int j0 = (bid - 64) * 24;
    for (int idx = t; idx < 24 * 104; idx += 256) {
      int jr = idx / 104, k = idx - jr * 104;
      int j = j0 + jr;
      float v = (j < NNODE && k < NNODE) ? Am[k * NNODE + j] : 0.f;
      ATp[j * 104 + k] = (_Float16)v;
    }
  }
}

// ---------------------------------------------------------------------------
// K1: Wh = X @ W. 1472 blocks x 512 thr, tile 64m x 512n, BK=32, dbuf.
//     Counted-vmcnt raw-barrier loop (never vmcnt(0) in steady state).
//     Conflict-free slot swizzle: sp = sl ^ ((row>>1)&3) on 64-B rows,
//     applied to A ds_write, B glds source, and fragment reads.
// ---------------------------------------------------------------------------
__global__ __launch_bounds__(512, 4) void gemm_kernel(
    const float* __restrict__ X, const _Float16* __restrict__ WT,
    const float* __restrict__ av, _Float16* __restrict__ Wh,
    float* __restrict__ Wh1g, float* __restrict__ Wh2g) {
  extern __shared__ char smem[];
  _Float16* Al0 = (_Float16*)(smem);            //  4096 B [64][32] swz
  _Float16* Al1 = (_Float16*)(smem + 4096);
  _Float16* Bl0 = (_Float16*)(smem + 8192);     // 32768 B [512][32] swz
  _Float16* Bl1 = (_Float16*)(smem + 40960);
  _Float16* tbuf = (_Float16*)smem;             // [64][513] epilogue
  float* red = (float*)smem;                    // [64][16] floats, 4096 B

  int t = threadIdx.x;
  int l = t & 63, w = t >> 6;
  unsigned m0 = (unsigned)blockIdx.x * 64u;

  // A path: thread t loads X[row=t>>3][4 floats at (t&7)*4], writes swizzled
  int arow = t >> 3, k8 = t & 7;
  const float* Xbase = X + ((size_t)m0 + arow) * FIN + k8 * 4;
  int awoff = arow * 64 + ((((k8 >> 1) ^ ((t >> 4) & 3)) << 4)) + (k8 & 1) * 8;

  // B glds: per instr, 16 rows x 64B; lane l -> row +(l>>2), slot_phys l&3;
  // source k-slot = (l&3) ^ ((l>>3)&3)
  int brow = l >> 2;
  int bsrc = ((l & 3) ^ ((l >> 3) & 3)) * 8;    // f16 units
  int bn[4];
  #pragma unroll
  for (int p = 0; p < 4; ++p) bn[p] = p * 128 + w * 16 + brow;

  // fragment reads: row = base + (l&15); sp = (l>>4) ^ ((l>>1)&3)
  int fsw = (((l >> 4) ^ ((l >> 1) & 3)) << 4);
  int aoff[4], boff[4];
  #pragma unroll
  for (int mi = 0; mi < 4; ++mi) aoff[mi] = (mi * 16 + (l & 15)) * 64 + fsw;
  #pragma unroll
  for (int ni = 0; ni < 4; ++ni) boff[ni] = (w * 64 + ni * 16 + (l & 15)) * 64 + fsw;

  float aC1[4], aC2[4];
  #pragma unroll
  for (int ni = 0; ni < 4; ++ni) {
    int C = w * 64 + ni * 16 + (l & 15);
    aC1[ni] = av[C];
    aC2[ni] = av[FOUT + C];
  }

  f32x4 zz = {0.f, 0.f, 0.f, 0.f};
  f32x4 acc[4][4];
  #pragma unroll
  for (int mi = 0; mi < 4; ++mi)
    #pragma unroll
    for (int ni = 0; ni < 4; ++ni) acc[mi][ni] = zz;

  f32x4 xvA, xvB;

#define K1_XLOAD(XV, KT) (XV) = *(const f32x4*)(Xbase + (size_t)(KT) * 32)

#define K1_GLDS(NB, KT) do {                                                   \
    _Pragma("unroll")                                                          \
    for (int p = 0; p < 4; ++p) {                                              \
      const _Float16* gp = WT + (size_t)bn[p] * FIN + (KT) * 32 + bsrc;        \
      char* lp = (char*)(NB) + p * 8192 + w * 1024;                            \
      __builtin_amdgcn_global_load_lds(                                        \
          (const __attribute__((address_space(1))) void*)gp,                   \
          (__attribute__((address_space(3))) void*)lp, 16, 0, 0);              \
    }                                                                          \
  } while (0)

#define K1_AWRITE(NA, XV) do {                                                 \
    half4 h;                                                                   \
    h[0] = (_Float16)(XV)[0]; h[1] = (_Float16)(XV)[1];                        \
    h[2] = (_Float16)(XV)[2]; h[3] = (_Float16)(XV)[3];                        \
    *(half4*)((char*)(NA) + awoff) = h;                                        \
  } while (0)

#define K1_MFMA(CA, CB) do {                                                   \
    half8 af[4], bf[4];                                                        \
    _Pragma("unroll")                                                          \
    for (int mi = 0; mi < 4; ++mi)                                             \
      af[mi] = *(const half8*)((const char*)(CA) + aoff[mi]);                  \
    _Pragma("unroll")                                                          \
    for (int ni = 0; ni < 4; ++ni)                                             \
      bf[ni] = *(const half8*)((const char*)(CB) + boff[ni]);                  \
    _Pragma("unroll")                                                          \
    for (int mi = 0; mi < 4; ++mi)                                             \
      _Pragma("unroll")                                                        \
      for (int ni = 0; ni < 4; ++ni)                                           \
        acc[mi][ni] = __builtin_amdgcn_mfma_f32_16x16x32_f16(                  \
            af[mi], bf[ni], acc[mi][ni], 0, 0, 0);                             \
  } while (0)

  // prologue: stage tile 0 fully; X(1) in flight
  K1_XLOAD(xvA, 0);
  K1_XLOAD(xvB, 1);
  K1_GLDS(Bl0, 0);
  K1_AWRITE(Al0, xvA);
  asm volatile("s_waitcnt vmcnt(0) lgkmcnt(0)" ::: "memory");
  __builtin_amdgcn_sched_barrier(0);
  __builtin_amdgcn_s_barrier();

  // steady: tiles kt (buf0) and kt+1 (buf1), kt = 0..28
  #pragma unroll 1
  for (int kt = 0; kt < 30; kt += 2) {
    // even phase: compute tile kt from Al0/Bl0
    K1_XLOAD(xvA, kt + 2);
    K1_GLDS(Bl1, kt + 1);
    K1_MFMA(Al0, Bl0);
    K1_AWRITE(Al1, xvB);                    // xvB = X(kt+1)
    asm volatile("s_waitcnt vmcnt(1)" ::: "memory");   // glds done, keep xvA
    asm volatile("s_waitcnt lgkmcnt(0)" ::: "memory");
    __builtin_amdgcn_sched_barrier(0);
    __builtin_amdgcn_s_barrier();
    // odd phase: compute tile kt+1 from Al1/Bl1
    K1_XLOAD(xvB, kt + 3);
    K1_GLDS(Bl0, kt + 2);
    K1_MFMA(Al1, Bl1);
    K1_AWRITE(Al0, xvA);                    // xvA = X(kt+2)
    asm volatile("s_waitcnt vmcnt(1)" ::: "memory");   // glds done, keep xvB
    asm volatile("s_waitcnt lgkmcnt(0)" ::: "memory");
    __builtin_amdgcn_sched_barrier(0);
    __builtin_amdgcn_s_barrier();
  }
  // tail: tiles 30, 31
  K1_GLDS(Bl1, 31);
  K1_MFMA(Al0, Bl0);
  K1_AWRITE(Al1, xvB);                      // xvB = X(31)
  asm volatile("s_waitcnt vmcnt(0) lgkmcnt(0)" ::: "memory");
  __builtin_amdgcn_sched_barrier(0);
  __builtin_amdgcn_s_barrier();
  K1_MFMA(Al1, Bl1);

  // ---- Wh1/Wh2: per-lane partials over 4 owned C-columns, shfl-reduce
  float p1[4][4], p2[4][4];
  #pragma unroll
  for (int mi = 0; mi < 4; ++mi)
    #pragma unroll
    for (int r = 0; r < 4; ++r) {
      float s1 = 0.f, s2 = 0.f;
      #pragma unroll
      for (int ni = 0; ni < 4; ++ni) {
        s1 = fmaf(acc[mi][ni][r], aC1[ni], s1);
        s2 = fmaf(acc[mi][ni][r], aC2[ni], s2);
      }
      p1[mi][r] = s1; p2[mi][r] = s2;
    }
  #pragma unroll
  for (int mm = 1; mm < 16; mm <<= 1)
    #pragma unroll
    for (int mi = 0; mi < 4; ++mi)
      #pragma unroll
      for (int r = 0; r < 4; ++r) {
        p1[mi][r] += __shfl_xor(p1[mi][r], mm);
        p2[mi][r] += __shfl_xor(p2[mi][r], mm);
      }
  if ((l & 15) == 0) {
    #pragma unroll
    for (int mi = 0; mi < 4; ++mi)
      #pragma unroll
      for (int r = 0; r < 4; ++r) {
        int m = mi * 16 + (l >> 4) * 4 + r;
        red[m * 16 + w * 2]     = p1[mi][r];
        red[m * 16 + w * 2 + 1] = p2[mi][r];
      }
  }
  __syncthreads();
  if (t < 64) {
    float s1 = 0.f, s2 = 0.f;
    #pragma unroll
    for (int w8 = 0; w8 < 8; ++w8) {
      s1 += red[t * 16 + w8 * 2];
      s2 += red[t * 16 + w8 * 2 + 1];
    }
    Wh1g[m0 + t] = s1;
    Wh2g[m0 + t] = s2;
  }
  __syncthreads();

  // ---- dump acc -> tbuf m-major [64][513]
  #pragma unroll
  for (int mi = 0; mi < 4; ++mi)
    #pragma unroll
    for (int ni = 0; ni < 4; ++ni) {
      int C = w * 64 + ni * 16 + (l & 15);
      #pragma unroll
      for (int r = 0; r < 4; ++r) {
        int m = mi * 16 + (l >> 4) * 4 + r;
        tbuf[m * 513 + C] = (_Float16)acc[mi][ni][r];
      }
    }
  __syncthreads();

  // ---- coalesced stores: thread t owns column C=t of Wh[b][f][96]
  unsigned mEnd = m0 + 64u;
  unsigned b0 = m0 / 92u;
  #pragma unroll 1
  for (unsigned seg = 0; seg < 2; ++seg) {
    unsigned bbase = b0 + seg;
    unsigned bstart = bbase * 92u;
    if (bstart >= mEnd) break;
    unsigned s = (bstart < m0) ? (m0 - bstart) : 0u;
    unsigned e = (mEnd - bstart < 92u) ? (mEnd - bstart) : 92u;
    if (s >= e) continue;
    _Float16* gp = Wh + ((size_t)bbase * FOUT + t) * 96;
    for (unsigned m8 = s & ~7u; m8 < e; m8 += 8) {
      unsigned lo = (m8 < s) ? s : m8;
      unsigned hi = (m8 + 8 > e) ? e : m8 + 8;
      if (hi - lo == 8) {
        half8 v;
        #pragma unroll
        for (int q = 0; q < 8; ++q)
          v[q] = tbuf[(bstart + lo - m0 + q) * 513 + t];
        *(half8*)(gp + lo) = v;
      } else {
        for (unsigned m = lo; m < hi; ++m)
          gp[m] = tbuf[(bstart + m - m0) * 513 + t];
      }
    }
  }
}

// ---------------------------------------------------------------------------
// K2: per-batch attention. QK+softmax from LDS (at_, e0a); PV over 8 chunks
//     of 64 f-rows, reg-staged (3 rotating sets, 2 chunks in flight under
//     QK), double-buffered LDS [64][104], one raw barrier per chunk.
// ---------------------------------------------------------------------------
__global__ __launch_bounds__(512, 4) void attn_kernel(
    const _Float16* __restrict__ Wh, const _Float16* __restrict__ ATp,
    const int* __restrict__ adj, const float* __restrict__ Wh1g,
    const float* __restrict__ Wh2g, const float* __restrict__ bias,
    float* __restrict__ out) {
  extern __shared__ char smem[];
  _Float16* at_  = (_Float16*)smem;                 // [96][104] 19968 B
  _Float16* e0a  = (_Float16*)(smem + 19968);       // [96][104] 19968 B
  _Float16* whc0 = (_Float16*)(smem + 39936);       // [64][104] 13312 B
  _Float16* whc1 = (_Float16*)(smem + 53248);       // [64][104] 13312 B
  float* w1s = (float*)(smem + 66560);              // [96]
  float* w2s = (float*)(smem + 66944);              // [96]

  int t = threadIdx.x, l = t & 63, w = t >> 6;
  int b = blockIdx.x;
  const _Float16* WhB = Wh + (size_t)b * FOUT * 96;

  // chunk staging: threads 0..383, 16 f16 each (one whc row = 6 threads)
  half8 st[3][2];
  bool stager = (t < 384);
  int srow = t / 6, scol = (t - srow * 6) * 16;

#define K2_LD(S, C) do { if (stager) {                                         \
    st[S][0] = *(const half8*)(WhB + (C) * 6144 + t * 16);                     \
    st[S][1] = *(const half8*)(WhB + (C) * 6144 + t * 16 + 8); } } while (0)
#define K2_WR(BUF, S) do { if (stager) {                                       \
    *(half8*)((BUF) + srow * 104 + scol)     = st[S][0];                       \
    *(half8*)((BUF) + srow * 104 + scol + 8) = st[S][1]; } } while (0)

  K2_LD(0, 0);
  K2_LD(1, 1);

  for (int idx = t; idx < 1248; idx += 512)
    *(half8*)(at_ + idx * 8) = *(const half8*)(ATp + idx * 8);
  if (t < 96) w1s[t] = (t < 92) ? Wh1g[(size_t)b * NNODE + t] : 0.f;
  else if (t < 192) {
    int j = t - 96;
    w2s[j] = (j < 92) ? Wh2g[(size_t)b * NNODE + j] : 0.f;
  }
  BAR_LGKM();

  // e0[i][k] = lrelu(Wh1[i]+Wh2[k]), zero-padded to [96][104]
  for (int idx = t; idx < 96 * 128; idx += 512) {
    int i = idx >> 7, k = idx & 127;
    if (k < 104) {
      float v = (i < 92 && k < 92) ? lrelu(w1s[i] + w2s[k]) : 0.f;
      e0a[i * 104 + k] = (_Float16)v;
    }
  }
  BAR_LGKM();

  if (w < 6) {
    f32x4 ez = {0.f, 0.f, 0.f, 0.f};
    f32x4 eacc[6];
    #pragma unroll
    for (int ni = 0; ni < 6; ++ni) eacc[ni] = ez;
    #pragma unroll
    for (int ks = 0; ks < 3; ++ks) {
      half8 ea = *(const half8*)((const char*)e0a +
                 (16 * w + (l & 15)) * 208 + ks * 64 + (l >> 4) * 16);
      #pragma unroll
      for (int ni = 0; ni < 6; ++ni) {
        half8 bt = *(const half8*)((const char*)at_ +
                   (16 * ni + (l & 15)) * 208 + ks * 64 + (l >> 4) * 16);
        eacc[ni] = __builtin_amdgcn_mfma_f32_16x16x32_f16(ea, bt, eacc[ni], 0, 0, 0);
      }
    }
    float attv[4][6];
    #pragma unroll
    for (int r = 0; r < 4; ++r) {
      int i = 16 * w + (l >> 4) * 4 + r;
      float s[6]; float m = -3.0e38f;
      #pragma unroll
      for (int ni = 0; ni < 6; ++ni) {
        int j = ni * 16 + (l & 15);
        float e = lrelu(eacc[ni][r]);
        float sv = -3.0e38f;
        if (i < 92 && j < 92) {
          int avj = adj[((size_t)b * NNODE + i) * NNODE + j];
          sv = (avj > 0) ? e : -9.0e15f;
        }
        s[ni] = sv;
        m = fmaxf(m, sv);
      }
      #pragma unroll
      for (int mm = 1; mm < 16; mm <<= 1) m = fmaxf(m, __shfl_xor(m, mm));
      float sum = 0.f; float p[6];
      #pragma unroll
      for (int ni = 0; ni < 6; ++ni) {
        int j = ni * 16 + (l & 15);
        p[ni] = (i < 92 && j < 92) ? __expf(s[ni] - m) : 0.f;
        sum += p[ni];
      }
      #pragma unroll
      for (int mm = 1; mm < 16; mm <<= 1) sum += __shfl_xor(sum, mm);
      float rs = (i < 92) ? (1.0f / sum) : 0.f;
      #pragma unroll
      for (int ni = 0; ni < 6; ++ni) attv[r][ni] = p[ni] * rs;
    }
    // att back into e0a (each wave touches only its own rows)
    #pragma unroll
    for (int r = 0; r < 4; ++r) {
      int i = 16 * w + (l >> 4) * 4 + r;
      #pragma unroll
      for (int ni = 0; ni < 6; ++ni)
        e0a[i * 104 + ni * 16 + (l & 15)] = (_Float16)attv[r][ni];
    }
  }
  BAR_LGKM();          // att visible to all waves

  K2_WR(whc0, 0);      // compiler waits vmcnt for set0 only
  BAR_LGKM();          // chunk 0 ready

  // PV: wave (ih = w>>2, fq = w&3): rows mi = ih*3+q, f-col fq*16+(l&15)
  int ih = w >> 2, fq = w & 3;
  #pragma unroll
  for (int c = 0; c < 8; ++c) {
    _Float16* cur = (c & 1) ? whc1 : whc0;
    _Float16* nxt = (c & 1) ? whc0 : whc1;
    if (c + 1 < 8) K2_WR(nxt, (c + 1) % 3);
    if (c + 2 < 8) K2_LD((c + 2) % 3, c + 2);
    f32x4 pz = {0.f, 0.f, 0.f, 0.f};
    f32x4 pacc[3];
    pacc[0] = pz; pacc[1] = pz; pacc[2] = pz;
    #pragma unroll
    for (int ks = 0; ks < 3; ++ks) {
      half8 bf = *(const half8*)((const char*)cur +
                 (fq * 16 + (l & 15)) * 208 + ks * 64 + (l >> 4) * 16);
      #pragma unroll
      for (int q = 0; q < 3; ++q) {
        half8 af = *(const half8*)((const char*)e0a +
                   (16 * (ih * 3 + q) + (l & 15)) * 208 + ks * 64 + (l >> 4) * 16);
        pacc[q] = __builtin_amdgcn_mfma_f32_16x16x32_f16(af, bf, pacc[q], 0, 0, 0);
      }
    }
    int fcol = c * 64 + fq * 16 + (l & 15);
    float bv = bias[fcol];
    #pragma unroll
    for (int q = 0; q < 3; ++q)
      #pragma unroll
      for (int r = 0; r < 4; ++r) {
        int i = 16 * (ih * 3 + q) + (l >> 4) * 4 + r;
        if (i < 92)
          out[((size_t)b * NNODE + i) * FOUT + fcol] = pacc[q][r] + bv;
      }
    if (c + 1 < 8) BAR_LGKM();
  }
}

// ---------------------------------------------------------------------------
extern "C" void kernel_launch(void* const* d_in, const int* in_sizes, int n_in,
                              void* d_out, int out_size, void* d_ws, size_t ws_size,
                              hipStream_t stream) {
  (void)in_sizes; (void)n_in; (void)out_size; (void)ws_size;
  const float* X    = (const float*)d_in[0];
  const int*   adj  = (const int*)d_in[1];
  const float* W    = (const float*)d_in[2];
  const float* av   = (const float*)d_in[3];
  const float* Am   = (const float*)d_in[4];
  const float* bias = (const float*)d_in[5];
  float* out = (float*)d_out;
  char* ws = (char*)d_ws;

  _Float16* WT  = (_Float16*)(ws);              // 1,048,576 B
  _Float16* ATp = (_Float16*)(ws + 1048576);    //    19,968 B
  float* Wh1 = (float*)(ws + 1068544);          //   376,832 B
  float* Wh2 = (float*)(ws + 1445376);          //   376,832 B
  _Float16* Wh = (_Float16*)(ws + 1822208);     // 100,663,296 B  [b][f][96]

  prep_kernel<<<68, 256, 0, stream>>>(W, Am, WT, ATp);
  hipFuncSetAttribute((const void*)gemm_kernel,
                      hipFuncAttributeMaxDynamicSharedMemorySize, 73728);
  gemm_kernel<<<1472, 512, 73728, stream>>>(X, WT, av, Wh, Wh1, Wh2);
  hipFuncSetAttribute((const void*)attn_kernel,
                      hipFuncAttributeMaxDynamicSharedMemorySize, 67584);
  attn_kernel<<<1024, 512, 67584, stream>>>(Wh, ATp, adj, Wh1, Wh2, bias, out);
}